// Round 6
// baseline (310.505 us; speedup 1.0000x reference)
//
#include <hip/hip_runtime.h>
#include <cmath>

#define IMG_H 4096
#define IMG_W 4096
#define GX 8
#define GY 64
#define TCOLS 512            /* output cols per block (256 thr x 2) */
#define R 64                 /* output rows per block */
#define NITER (R + 10)       /* 74 = 6*11 + 8 */

struct GW { float w[11]; };

__device__ __forceinline__ int clampi(int v, int lo, int hi) {
  return v < lo ? lo : (v > hi ? hi : v);
}

// Barrier-free sweep: no LDS staging. Each thread loads its own 14-word
// window per row as 7 coalesced float2 (lane-stride 8B -> 512B/wave/inst),
// overlap between lanes served by L1. Row base is wave-uniform (SGPR add).
// Vertical conv via an 11-slot register ring; ring indices are all static
// (11-phase unrolled groups, interior groups branch-free).
__global__ __launch_bounds__(256) void ssim_sweep_kernel(
    const float* __restrict__ img1, const float* __restrict__ img2,
    float* __restrict__ partial, GW gw) {
  const int tid = threadIdx.x;
  const int bx = blockIdx.x, by = blockIdx.y;
  const int c0   = bx * TCOLS;
  const int row0 = by * R;
  const int base_col = c0 + 2 * tid - 6;   // window words [base_col, base_col+13]
  // lanes whose 14-word span leaves the image (3 lanes at each image edge)
  const bool cl = (base_col < 0) || (base_col + 13 > IMG_W - 1);

  float acc[5][11][2];
  #pragma unroll
  for (int ch = 0; ch < 5; ++ch)
    #pragma unroll
    for (int s = 0; s < 11; ++s) { acc[ch][s][0] = 0.f; acc[ch][s][1] = 0.f; }
  float sum = 0.f;
  const float C1 = 6.5025f, C2 = 58.5225f;

  auto do_phase = [&](int i, int p, bool consume, bool clampRow) {
    int gr = row0 - 5 + i;
    if (clampRow) gr = clampi(gr, 0, IMG_H - 1);
    const float* r1 = img1 + (long)gr * IMG_W;
    const float* r2 = img2 + (long)gr * IMG_W;

    float wa[14], wb[14];
    if (!cl) {
      #pragma unroll
      for (int m = 0; m < 7; ++m) {
        float2 fa = *reinterpret_cast<const float2*>(r1 + base_col + 2 * m);
        float2 fb = *reinterpret_cast<const float2*>(r2 + base_col + 2 * m);
        wa[2 * m] = fa.x; wa[2 * m + 1] = fa.y;
        wb[2 * m] = fb.x; wb[2 * m + 1] = fb.y;
      }
    } else {
      wa[0] = wa[13] = wb[0] = wb[13] = 0.f;   // unused elements
      #pragma unroll
      for (int e = 1; e <= 12; ++e) {
        int gc = clampi(base_col + e, 0, IMG_W - 1);
        wa[e] = r1[gc]; wb[e] = r2[gc];
      }
    }

    // fused 5-channel horizontal conv for 2 columns (element-centric)
    float h[5][2];
    #pragma unroll
    for (int ch = 0; ch < 5; ++ch) { h[ch][0] = 0.f; h[ch][1] = 0.f; }
    #pragma unroll
    for (int e = 1; e <= 12; ++e) {
      const float a = wa[e], b = wb[e];
      const float aa = a * a, bb = b * b, ab = a * b;
      if (e <= 11) {               // tap j = e-1 for col 0
        const float w0 = gw.w[e - 1];
        h[0][0] = fmaf(w0, a,  h[0][0]);
        h[1][0] = fmaf(w0, b,  h[1][0]);
        h[2][0] = fmaf(w0, aa, h[2][0]);
        h[3][0] = fmaf(w0, bb, h[3][0]);
        h[4][0] = fmaf(w0, ab, h[4][0]);
      }
      if (e >= 2) {                // tap j = e-2 for col 1
        const float w1 = gw.w[e - 2];
        h[0][1] = fmaf(w1, a,  h[0][1]);
        h[1][1] = fmaf(w1, b,  h[1][1]);
        h[2][1] = fmaf(w1, aa, h[2][1]);
        h[3][1] = fmaf(w1, bb, h[3][1]);
        h[4][1] = fmaf(w1, ab, h[4][1]);
      }
    }

    // scatter into the 11 pending output rows; d=+5 slot starts fresh (mul)
    #pragma unroll
    for (int d = -5; d <= 5; ++d) {
      const int s = (p + d + 11) % 11;
      const float wd = gw.w[5 - d];
      if (d == 5) {
        #pragma unroll
        for (int ch = 0; ch < 5; ++ch) {
          acc[ch][s][0] = wd * h[ch][0];
          acc[ch][s][1] = wd * h[ch][1];
        }
      } else {
        #pragma unroll
        for (int ch = 0; ch < 5; ++ch) {
          acc[ch][s][0] = fmaf(wd, h[ch][0], acc[ch][s][0]);
          acc[ch][s][1] = fmaf(wd, h[ch][1], acc[ch][s][1]);
        }
      }
    }

    if (consume) {                  // output row i-10 complete
      const int cs = (p + 6) % 11;
      #pragma unroll
      for (int x = 0; x < 2; ++x) {
        float mu1 = acc[0][cs][x], mu2 = acc[1][cs][x];
        float x2 = acc[2][cs][x], y2 = acc[3][cs][x], xy = acc[4][cs][x];
        float mu1s = mu1 * mu1, mu2s = mu2 * mu2, m12 = mu1 * mu2;
        float num = (2.f * m12 + C1) * (2.f * (xy - m12) + C2);
        float den = (mu1s + mu2s + C1) * ((x2 - mu1s) + (y2 - mu2s) + C2);
        sum += num * __builtin_amdgcn_rcpf(den);
      }
    }
  };

  // group 0: i=0..10, top-edge row clamp, first consume at p=10
  #pragma unroll
  for (int p = 0; p < 11; ++p) do_phase(p, p, p == 10, true);

  // interior groups: i=11..65 -> gr in [row0+6, row0+60], always in-bounds;
  // branch-free unrolled bodies let the compiler pipeline loads across phases
  for (int g = 1; g < 6; ++g) {
    #pragma unroll
    for (int p = 0; p < 11; ++p) do_phase(g * 11 + p, p, true, false);
  }

  // tail: i=66..73, bottom-edge row clamp
  #pragma unroll
  for (int p = 0; p < 8; ++p) do_phase(66 + p, p, true, true);

  // ---- block reduction ----
  #pragma unroll
  for (int off = 32; off > 0; off >>= 1) sum += __shfl_down(sum, off);
  __shared__ float wsum[4];
  if ((tid & 63) == 0) wsum[tid >> 6] = sum;
  __syncthreads();
  if (tid == 0)
    partial[by * GX + bx] = wsum[0] + wsum[1] + wsum[2] + wsum[3];
}

__global__ __launch_bounds__(256) void ssim_reduce_kernel(
    const float* __restrict__ partial, float* __restrict__ out) {
  int tid = threadIdx.x;
  double s = (double)partial[tid] + (double)partial[tid + 256];  // 512 partials
  #pragma unroll
  for (int off = 32; off > 0; off >>= 1) s += __shfl_down(s, off);
  __shared__ double ws[4];
  if ((tid & 63) == 0) ws[tid >> 6] = s;
  __syncthreads();
  if (tid == 0)
    out[0] = (float)((ws[0] + ws[1] + ws[2] + ws[3]) /
                     ((double)IMG_H * (double)IMG_W));
}

extern "C" void kernel_launch(void* const* d_in, const int* in_sizes, int n_in,
                              void* d_out, int out_size, void* d_ws, size_t ws_size,
                              hipStream_t stream) {
  const float* img1 = (const float*)d_in[0];
  const float* img2 = (const float*)d_in[1];
  float* partial = (float*)d_ws;
  float* out = (float*)d_out;

  GW gw;
  double g[11], s = 0.0;
  for (int i = 0; i < 11; ++i) {
    double x = i - 5.0;
    g[i] = exp(-(x * x) / (2.0 * 1.5 * 1.5));
    s += g[i];
  }
  for (int i = 0; i < 11; ++i) gw.w[i] = (float)(g[i] / s);

  dim3 grid(GX, GY);
  ssim_sweep_kernel<<<grid, 256, 0, stream>>>(img1, img2, partial, gw);
  ssim_reduce_kernel<<<1, 256, 0, stream>>>(partial, out);
}

// Round 7
// 220.717 us; speedup vs baseline: 1.4068x; 1.4068x over previous
//
#include <hip/hip_runtime.h>
#include <cmath>

#define IMG_H 4096
#define IMG_W 4096
#define GX 8
#define GY 64
#define TCOLS 512            /* output cols per block (256 thr x 2) */
#define R 64                 /* output rows per block */
/* input rows per block = 74 = 18 groups of 4 + group 18 (2 used) */

struct GW { float w[11]; };

__device__ __forceinline__ int clampi(int v, int lo, int hi) {
  return v < lo ? lo : (v > hi ? hi : v);
}

// Row-sweep with 4-row barrier amortization:
//  - LDS stages raw img rows (broadcast serves the 7x horizontal window
//    overlap; round 6 proved direct-global loads lose 2x here).
//  - Barrier per 4-row group (19 total) instead of per row (74): each sync
//    covers ~2300 cyc of compute instead of ~580.
//  - Vertical conv in a 12-slot register ring; 12-row macro iterations make
//    every ring index compile-time static (12 = LCM(4-row groups, ring)).
//  - launch_bounds has NO min-wave arg: round 4 showed arg>=4 forces a
//    64-VGPR cap and spills the ring (983 MB scratch, 5x slowdown).
__global__ __launch_bounds__(256) void ssim_sweep_kernel(
    const float* __restrict__ img1, const float* __restrict__ img2,
    float* __restrict__ partial, GW gw) {
  __shared__ __align__(16) float sbuf[2][4][2][528];  /* [buf][row][img][word] 33 KB */

  const int tid = threadIdx.x;
  const int bx = blockIdx.x, by = blockIdx.y;
  const int c0   = bx * TCOLS;
  const int row0 = by * R;

  float4 P[5];
  const int nslot = (tid < 32) ? 5 : 4;   /* 1056 float4 slots / 256 threads */

  // group g = input rows 4g..4g+3 (gr = row0-5+i); slot j -> (row, img, word)
  auto prefetch = [&](int g) {
    #pragma unroll
    for (int k = 0; k < 5; ++k) {
      if (k < nslot) {
        int j  = tid + (k << 8);
        int rr = j / 264;
        int q  = j - 264 * rr;
        const float* img = (q < 132) ? img1 : img2;
        int w4 = ((q < 132) ? q : q - 132) << 2;
        int gr = clampi(row0 - 5 + 4 * g + rr, 0, IMG_H - 1);
        const float* rp = img + (long)gr * IMG_W;
        int gc = c0 - 8 + w4;
        if (gc >= 0 && gc + 3 < IMG_W) {
          P[k] = *reinterpret_cast<const float4*>(rp + gc);
        } else {                      // edge blocks: replicate-clamped scalar
          P[k].x = rp[clampi(gc + 0, 0, IMG_W - 1)];
          P[k].y = rp[clampi(gc + 1, 0, IMG_W - 1)];
          P[k].z = rp[clampi(gc + 2, 0, IMG_W - 1)];
          P[k].w = rp[clampi(gc + 3, 0, IMG_W - 1)];
        }
      }
    }
  };
  auto commit = [&](int g) {
    const int buf = g & 1;
    #pragma unroll
    for (int k = 0; k < 5; ++k) {
      if (k < nslot) {
        int j  = tid + (k << 8);
        int rr = j / 264;
        int q  = j - 264 * rr;
        int im = (q < 132) ? 0 : 1;
        int w4 = ((q < 132) ? q : q - 132) << 2;
        *reinterpret_cast<float4*>(&sbuf[buf][rr][im][w4]) = P[k];
      }
    }
  };

  float acc[5][12][2];   // 12-slot ring; output o lives in slot o%12
  float sum = 0.f;
  const float C1 = 6.5025f, C2 = 58.5225f;
  const int base = 2 * tid + 2;   // staged words [base, base+15], use [1..12]

  // p = i % 12 (compile-time), row-in-group = p & 3
  auto compute_row = [&](int p, bool consume, int cur) {
    const int r = p & 3;
    float wa[14], wb[14];
    #pragma unroll
    for (int m = 0; m < 7; ++m) {
      float2 fa = *reinterpret_cast<const float2*>(&sbuf[cur][r][0][base + 2 * m]);
      float2 fb = *reinterpret_cast<const float2*>(&sbuf[cur][r][1][base + 2 * m]);
      wa[2 * m] = fa.x; wa[2 * m + 1] = fa.y;
      wb[2 * m] = fb.x; wb[2 * m + 1] = fb.y;
    }
    // fused 5-channel horizontal conv, element-centric, 2 cols
    float h[5][2];
    #pragma unroll
    for (int ch = 0; ch < 5; ++ch) { h[ch][0] = 0.f; h[ch][1] = 0.f; }
    #pragma unroll
    for (int e = 1; e <= 12; ++e) {
      const float a = wa[e], b = wb[e];
      const float aa = a * a, bb = b * b, ab = a * b;
      if (e <= 11) {
        const float w0 = gw.w[e - 1];
        h[0][0] = fmaf(w0, a,  h[0][0]);
        h[1][0] = fmaf(w0, b,  h[1][0]);
        h[2][0] = fmaf(w0, aa, h[2][0]);
        h[3][0] = fmaf(w0, bb, h[3][0]);
        h[4][0] = fmaf(w0, ab, h[4][0]);
      }
      if (e >= 2) {
        const float w1 = gw.w[e - 2];
        h[0][1] = fmaf(w1, a,  h[0][1]);
        h[1][1] = fmaf(w1, b,  h[1][1]);
        h[2][1] = fmaf(w1, aa, h[2][1]);
        h[3][1] = fmaf(w1, bb, h[3][1]);
        h[4][1] = fmaf(w1, ab, h[4][1]);
      }
    }
    // scatter: input i feeds outputs o=i-10+t (t=0..10), slot (p+2+t)%12,
    // weight w[10-t]; t=10 is output o=i's first contribution -> mul init
    #pragma unroll
    for (int t = 0; t <= 10; ++t) {
      const int s = (p + 2 + t) % 12;
      const float wd = gw.w[10 - t];
      if (t == 10) {
        #pragma unroll
        for (int ch = 0; ch < 5; ++ch) {
          acc[ch][s][0] = wd * h[ch][0];
          acc[ch][s][1] = wd * h[ch][1];
        }
      } else {
        #pragma unroll
        for (int ch = 0; ch < 5; ++ch) {
          acc[ch][s][0] = fmaf(wd, h[ch][0], acc[ch][s][0]);
          acc[ch][s][1] = fmaf(wd, h[ch][1], acc[ch][s][1]);
        }
      }
    }
    if (consume) {   // output o=i-10 complete in slot (p+2)%12
      const int cs = (p + 2) % 12;
      #pragma unroll
      for (int x = 0; x < 2; ++x) {
        float mu1 = acc[0][cs][x], mu2 = acc[1][cs][x];
        float x2 = acc[2][cs][x], y2 = acc[3][cs][x], xy = acc[4][cs][x];
        float mu1s = mu1 * mu1, mu2s = mu2 * mu2, m12 = mu1 * mu2;
        float num = (2.f * m12 + C1) * (2.f * (xy - m12) + C2);
        float den = (mu1s + mu2s + C1) * ((x2 - mu1s) + (y2 - mu2s) + C2);
        sum += num * __builtin_amdgcn_rcpf(den);
      }
    }
  };

  // prologue: stage group 0
  prefetch(0);
  commit(0);
  __syncthreads();

  // 6 macros x 12 rows (3 groups); rows i = 12M+p, phase p static
  for (int M = 0; M < 6; ++M) {
    #pragma unroll
    for (int sub = 0; sub < 3; ++sub) {
      const int g = 3 * M + sub;
      prefetch(g + 1);                 // next group's loads fly under compute
      #pragma unroll
      for (int r = 0; r < 4; ++r) {
        const int p = sub * 4 + r;
        compute_row(p, (M > 0) || (p >= 10), g & 1);
      }
      commit(g + 1);                   // vmcnt drain inserted by compiler
      __syncthreads();                 // one barrier per 4 rows
    }
  }
  // tail: rows 72,73 (phases 0,1) from group 18 in buf[0]
  compute_row(0, true, 0);
  compute_row(1, true, 0);

  // ---- block reduction ----
  #pragma unroll
  for (int off = 32; off > 0; off >>= 1) sum += __shfl_down(sum, off);
  __shared__ float wsum[4];
  if ((tid & 63) == 0) wsum[tid >> 6] = sum;
  __syncthreads();
  if (tid == 0)
    partial[by * GX + bx] = wsum[0] + wsum[1] + wsum[2] + wsum[3];
}

__global__ __launch_bounds__(256) void ssim_reduce_kernel(
    const float* __restrict__ partial, float* __restrict__ out) {
  int tid = threadIdx.x;
  double s = (double)partial[tid] + (double)partial[tid + 256];  // 512 partials
  #pragma unroll
  for (int off = 32; off > 0; off >>= 1) s += __shfl_down(s, off);
  __shared__ double ws[4];
  if ((tid & 63) == 0) ws[tid >> 6] = s;
  __syncthreads();
  if (tid == 0)
    out[0] = (float)((ws[0] + ws[1] + ws[2] + ws[3]) /
                     ((double)IMG_H * (double)IMG_W));
}

extern "C" void kernel_launch(void* const* d_in, const int* in_sizes, int n_in,
                              void* d_out, int out_size, void* d_ws, size_t ws_size,
                              hipStream_t stream) {
  const float* img1 = (const float*)d_in[0];
  const float* img2 = (const float*)d_in[1];
  float* partial = (float*)d_ws;
  float* out = (float*)d_out;

  GW gw;
  double g[11], s = 0.0;
  for (int i = 0; i < 11; ++i) {
    double x = i - 5.0;
    g[i] = exp(-(x * x) / (2.0 * 1.5 * 1.5));
    s += g[i];
  }
  for (int i = 0; i < 11; ++i) gw.w[i] = (float)(g[i] / s);

  dim3 grid(GX, GY);
  ssim_sweep_kernel<<<grid, 256, 0, stream>>>(img1, img2, partial, gw);
  ssim_reduce_kernel<<<1, 256, 0, stream>>>(partial, out);
}

// Round 8
// 194.451 us; speedup vs baseline: 1.5968x; 1.1351x over previous
//
#include <hip/hip_runtime.h>
#include <cmath>

#define IMG_H 4096
#define IMG_W 4096
#define GX 8
#define GY 64
#define TCOLS 512            /* output cols per block (256 thr x 2) */
#define R 64                 /* output rows per block */
#define NITER (R + 10)       /* 74 h-rows per strip */
#define SWORDS 528           /* staged words per img-row: [c0-8, c0+520) */
#define NF4 132              /* float4 slots per img per row */
#define NSLOT (2*NF4)        /* 264 */

struct GW { float w[11]; };

__device__ __forceinline__ int clampi(int v, int lo, int hi) {
  return v < lo ? lo : (v > hi ? hi : v);
}

// Round-3 skeleton (best measured: 106 us) + 4-channel algebra:
// SSIM only needs sigma1^2+sigma2^2 as a SUM, so convolve c3=G*(x^2+y^2)
// instead of G*x^2 and G*y^2 separately. 5->4 conv channels: h-conv and
// vertical scatter drop 20% of their FMAs, ring shrinks 110->88 VGPRs.
// Lessons kept: LDS broadcast staging (round 6: direct-global = 2x loss),
// per-row barrier (round 7: amortizing barriers did NOT help), no min-wave
// launch_bounds arg >2 (round 4: forces 64-VGPR cap, spills ring).
__global__ __launch_bounds__(256, 2) void ssim_sweep_kernel(
    const float* __restrict__ img1, const float* __restrict__ img2,
    float* __restrict__ partial, GW gw) {
  __shared__ __align__(16) float sbuf[2][2][SWORDS];

  const int tid  = threadIdx.x;
  const int bx = blockIdx.x, by = blockIdx.y;
  const int c0   = bx * TCOLS;
  const int row0 = by * R;
  const bool edge = (bx == 0) || (bx == GX - 1);

  const int  j0   = tid;                 // staging slot 0..255
  const bool has2 = (tid < NSLOT - 256); // 8 threads take a 2nd slot
  const int  j1   = tid + 256;

  auto load_slot = [&](int j, int gr) -> float4 {
    const float* img = (j < NF4) ? img1 : img2;
    int wo = ((j < NF4) ? j : j - NF4) * 4;
    long rowbase = (long)gr * IMG_W;
    int gc = c0 - 8 + wo;
    if (!edge) {
      return *reinterpret_cast<const float4*>(img + rowbase + gc);
    } else {
      float4 v;
      v.x = img[rowbase + clampi(gc + 0, 0, IMG_W - 1)];
      v.y = img[rowbase + clampi(gc + 1, 0, IMG_W - 1)];
      v.z = img[rowbase + clampi(gc + 2, 0, IMG_W - 1)];
      v.w = img[rowbase + clampi(gc + 3, 0, IMG_W - 1)];
      return v;
    }
  };
  auto store_slot = [&](int buf, int j, float4 v) {
    int im = (j < NF4) ? 0 : 1;
    int wo = ((j < NF4) ? j : j - NF4) * 4;
    *reinterpret_cast<float4*>(&sbuf[buf][im][wo]) = v;
  };

  // ---- prologue: stage h-row 0 into buffer 0 ----
  {
    int gr = clampi(row0 - 5, 0, IMG_H - 1);
    float4 v0 = load_slot(j0, gr);
    store_slot(0, j0, v0);
    if (has2) { float4 v1 = load_slot(j1, gr); store_slot(0, j1, v1); }
  }

  // ring: 4 channels {mu1, mu2, E[x^2+y^2], E[xy]} x 11 slots x 2 cols
  // output row t lives in slot (t+1)%11 relative below: slot(m)=(p+1+m)%11
  float acc[4][11][2];
  float sum = 0.f;
  const float C1 = 6.5025f, C2 = 58.5225f;
  const int base = 2 * tid + 2;   // first staged word of this thread's window

  for (int g = 0; g < 7; ++g) {
    #pragma unroll
    for (int p = 0; p < 11; ++p) {
      const int i = g * 11 + p;
      if (i < NITER) {
        __syncthreads();   // iter i-1 writes of buf[i&1] visible

        // prefetch next input row (global -> regs), hidden under compute
        float4 pre0, pre1;
        const bool pf = (i + 1 < NITER);
        if (pf) {
          int gr = clampi(row0 - 5 + i + 1, 0, IMG_H - 1);
          pre0 = load_slot(j0, gr);
          if (has2) pre1 = load_slot(j1, gr);
        }

        const int cur = i & 1;
        // window: staged words [2tid+2, 2tid+16); used: [1..12]
        float wa[14], wb[14];
        #pragma unroll
        for (int m = 0; m < 7; ++m) {
          float2 fa = *reinterpret_cast<const float2*>(&sbuf[cur][0][base + 2 * m]);
          float2 fb = *reinterpret_cast<const float2*>(&sbuf[cur][1][base + 2 * m]);
          wa[2 * m] = fa.x; wa[2 * m + 1] = fa.y;
          wb[2 * m] = fb.x; wb[2 * m + 1] = fb.y;
        }

        // fused 4-channel horizontal conv, element-centric, 2 cols
        float h[4][2];
        #pragma unroll
        for (int ch = 0; ch < 4; ++ch) { h[ch][0] = 0.f; h[ch][1] = 0.f; }
        #pragma unroll
        for (int e = 1; e <= 12; ++e) {
          const float a = wa[e], b = wb[e];
          const float sq = fmaf(b, b, a * a);   // x^2 + y^2
          const float ab = a * b;               // x*y
          if (e <= 11) {               // tap j = e-1 for col 0
            const float w0 = gw.w[e - 1];
            h[0][0] = fmaf(w0, a,  h[0][0]);
            h[1][0] = fmaf(w0, b,  h[1][0]);
            h[2][0] = fmaf(w0, sq, h[2][0]);
            h[3][0] = fmaf(w0, ab, h[3][0]);
          }
          if (e >= 2) {                // tap j = e-2 for col 1
            const float w1 = gw.w[e - 2];
            h[0][1] = fmaf(w1, a,  h[0][1]);
            h[1][1] = fmaf(w1, b,  h[1][1]);
            h[2][1] = fmaf(w1, sq, h[2][1]);
            h[3][1] = fmaf(w1, ab, h[3][1]);
          }
        }

        // scatter: input row i feeds outputs t=i-10+m (m=0..10),
        // slot (p+1+m)%11, weight w[10-m]; m=10 starts output t=i -> mul
        #pragma unroll
        for (int m = 0; m <= 10; ++m) {
          const int s = (p + 1 + m) % 11;
          const float wd = gw.w[10 - m];
          if (m == 10) {
            #pragma unroll
            for (int ch = 0; ch < 4; ++ch) {
              acc[ch][s][0] = wd * h[ch][0];
              acc[ch][s][1] = wd * h[ch][1];
            }
          } else {
            #pragma unroll
            for (int ch = 0; ch < 4; ++ch) {
              acc[ch][s][0] = fmaf(wd, h[ch][0], acc[ch][s][0]);
              acc[ch][s][1] = fmaf(wd, h[ch][1], acc[ch][s][1]);
            }
          }
        }

        // output row t=i-10 complete in slot (p+1)%11 -> SSIM + sum
        if (i >= 10) {
          const int cs = (p + 1) % 11;
          #pragma unroll
          for (int x = 0; x < 2; ++x) {
            float mu1 = acc[0][cs][x], mu2 = acc[1][cs][x];
            float s3  = acc[2][cs][x], s4  = acc[3][cs][x];
            float mu1s = mu1 * mu1, mu2s = mu2 * mu2, m12 = mu1 * mu2;
            float num = (2.f * m12 + C1) * (2.f * (s4 - m12) + C2);
            float den = (mu1s + mu2s + C1) * ((s3 - mu1s - mu2s) + C2);
            sum += num * __builtin_amdgcn_rcpf(den);
          }
        }

        // commit prefetched row to the other buffer
        if (pf) {
          store_slot((i + 1) & 1, j0, pre0);
          if (has2) store_slot((i + 1) & 1, j1, pre1);
        }
      }
    }
  }

  // ---- block reduction ----
  #pragma unroll
  for (int off = 32; off > 0; off >>= 1) sum += __shfl_down(sum, off);
  __shared__ float wsum[4];
  if ((tid & 63) == 0) wsum[tid >> 6] = sum;
  __syncthreads();
  if (tid == 0)
    partial[by * GX + bx] = wsum[0] + wsum[1] + wsum[2] + wsum[3];
}

__global__ __launch_bounds__(256) void ssim_reduce_kernel(
    const float* __restrict__ partial, float* __restrict__ out) {
  int tid = threadIdx.x;
  double s = (double)partial[tid] + (double)partial[tid + 256];  // 512 partials
  #pragma unroll
  for (int off = 32; off > 0; off >>= 1) s += __shfl_down(s, off);
  __shared__ double ws[4];
  if ((tid & 63) == 0) ws[tid >> 6] = s;
  __syncthreads();
  if (tid == 0)
    out[0] = (float)((ws[0] + ws[1] + ws[2] + ws[3]) /
                     ((double)IMG_H * (double)IMG_W));
}

extern "C" void kernel_launch(void* const* d_in, const int* in_sizes, int n_in,
                              void* d_out, int out_size, void* d_ws, size_t ws_size,
                              hipStream_t stream) {
  const float* img1 = (const float*)d_in[0];
  const float* img2 = (const float*)d_in[1];
  float* partial = (float*)d_ws;
  float* out = (float*)d_out;

  GW gw;
  double g[11], s = 0.0;
  for (int i = 0; i < 11; ++i) {
    double x = i - 5.0;
    g[i] = exp(-(x * x) / (2.0 * 1.5 * 1.5));
    s += g[i];
  }
  for (int i = 0; i < 11; ++i) gw.w[i] = (float)(g[i] / s);

  dim3 grid(GX, GY);
  ssim_sweep_kernel<<<grid, 256, 0, stream>>>(img1, img2, partial, gw);
  ssim_reduce_kernel<<<1, 256, 0, stream>>>(partial, out);
}